// Round 6
// baseline (253.652 us; speedup 1.0000x reference)
//
#include <hip/hip_runtime.h>
#include <hip/hip_bf16.h>

#define TT 2048
#define HB 64
#define NB 16
#define NSPLIT 4

typedef __attribute__((ext_vector_type(8))) short short8;
typedef __attribute__((ext_vector_type(4))) float floatx4;

static __device__ __forceinline__ unsigned short f2bf(float f) {
  __hip_bfloat16 h = __float2bfloat16(f);
  return *reinterpret_cast<unsigned short*>(&h);
}
static __device__ __forceinline__ float bf2f(unsigned short u) {
  __hip_bfloat16 h = *reinterpret_cast<__hip_bfloat16*>(&u);
  return __bfloat162float(h);
}

// ---------------------------------------------------------------------------
// Prep: Wt[mat][n][k] = bf16(W[k][n])  (3x64x512), Erb = bf16(Er) (2048x64).
// ---------------------------------------------------------------------------
__global__ __launch_bounds__(256) void prep_kernel(
    const float* __restrict__ Wq, const float* __restrict__ Wk,
    const float* __restrict__ Wv, const float* __restrict__ Er,
    unsigned short* __restrict__ Wt, unsigned short* __restrict__ Erb) {
  const int bx = blockIdx.x, tid = threadIdx.x;
  if (bx < 512) {
    int idx = bx * 256 + tid;
    Erb[idx] = f2bf(Er[idx]);
  } else {
    int n = bx - 512;  // 0..63
    const float* Ws[3] = {Wq, Wk, Wv};
#pragma unroll
    for (int m = 0; m < 3; m++)
      for (int k = tid; k < 512; k += 256)
        Wt[(size_t)(m * 64 + n) * 512 + k] = f2bf(Ws[m][(size_t)k * 64 + n]);
  }
}

// ---------------------------------------------------------------------------
// Projections via MFMA, no LDS. Block 256 (4 waves), 64 rows/block,
// 16 rows/wave, 12 n-tiles (q:0-3, k:4-7, v:8-11). A-frags from global x
// (fp32->bf16 in regs); B-frags from Wt (L2). vT stored [B][H][T].
// ---------------------------------------------------------------------------
__global__ __launch_bounds__(256) void proj_kernel(
    const float* __restrict__ x, const unsigned short* __restrict__ Wt,
    unsigned short* __restrict__ qb, unsigned short* __restrict__ kb,
    unsigned short* __restrict__ vT) {
  const int tid = threadIdx.x;
  const int w = tid >> 6, l = tid & 63, quad = l >> 4, lm = l & 15;
  const int m0 = blockIdx.x * 64;
  const int row_a = m0 + w * 16 + lm;

  floatx4 acc[12];
#pragma unroll
  for (int i = 0; i < 12; i++) acc[i] = (floatx4){0.f, 0.f, 0.f, 0.f};

  for (int kt = 0; kt < 512; kt += 64) {
    short8 af[2];
#pragma unroll
    for (int kc = 0; kc < 2; kc++) {
      const float* px = &x[(size_t)row_a * 512 + kt + kc * 32 + quad * 8];
      float4 f0 = *(const float4*)px;
      float4 f1 = *(const float4*)(px + 4);
      short8 s;
      s[0] = f2bf(f0.x); s[1] = f2bf(f0.y); s[2] = f2bf(f0.z); s[3] = f2bf(f0.w);
      s[4] = f2bf(f1.x); s[5] = f2bf(f1.y); s[6] = f2bf(f1.z); s[7] = f2bf(f1.w);
      af[kc] = s;
    }
#pragma unroll
    for (int nt = 0; nt < 12; nt++) {
      const unsigned short* pw =
          &Wt[(size_t)((nt >> 2) * 64 + (nt & 3) * 16 + lm) * 512 + kt + quad * 8];
      short8 b0 = *(const short8*)pw;
      short8 b1 = *(const short8*)(pw + 32);
      acc[nt] = __builtin_amdgcn_mfma_f32_16x16x32_bf16(af[0], b0, acc[nt], 0, 0, 0);
      acc[nt] = __builtin_amdgcn_mfma_f32_16x16x32_bf16(af[1], b1, acc[nt], 0, 0, 0);
    }
  }
  const int b = m0 >> 11;
#pragma unroll
  for (int nt = 0; nt < 12; nt++) {
    int col = (nt & 3) * 16 + lm;
#pragma unroll
    for (int rg = 0; rg < 4; rg++) {
      int row = m0 + w * 16 + quad * 4 + rg;
      unsigned short hv = f2bf(acc[nt][rg]);
      if (nt < 4) qb[(size_t)row * 64 + col] = hv;
      else if (nt < 8) kb[(size_t)row * 64 + col] = hv;
      else vT[(size_t)(b * 64 + col) * 2048 + (row & 2047)] = hv;
    }
  }
}

// ---------------------------------------------------------------------------
// Flash relative attention. Block = 4 waves = the 4 j-splits of one
// (batch, pair): phase 0 = i-tile pr, phase 1 = i-tile 63-pr. Uniform work,
// 512 blocks (2/CU), in-block split merge, direct out write.
// NO fences in the K-loop: same-wave LDS RAW/WAR is guaranteed by the
// in-order per-wave DS pipe + compiler register tracking; removing the
// lgkmcnt(0)/sched_barrier fences lets global loads span phases.
// ROTATED-LOAD PIPELINE (no extra regs): vf loaded at body top (used ~1000cy
// later at PV); next tile's kf/uf/ef issued right after their last use, so
// their L2 latency hides under softmax+PV of the current tile.
// PURE-TILE PATH (d>=64, all but <=1 tile/wave-phase): no masking, Ds gather
// collapses to per-lane base + static imm offsets (16 x ds_read_b32).
// DEFER-MAX (THR=8) fast path as R5. Batches {x,x+8} pinned to XCD x.
//   S[i][j] = 0.125*(q_i.k_j) + [ db_i (j==i) | 0 (j==i-1) |
//                                 q_{j+1}.Er[i-j-2] (j<=i-2) ]
// ---------------------------------------------------------------------------
#define SLICE_B 11264  // per-wave slice: Ds 8448 | Ps 2560 | dbv 128
                       // epilogue reuse: Os [32][65] f32 (8320) | m/l 256

__global__ __launch_bounds__(256, 2) void attn_kernel(
    const unsigned short* __restrict__ qb, const unsigned short* __restrict__ kb,
    const unsigned short* __restrict__ vT, const unsigned short* __restrict__ Erb,
    float* __restrict__ out) {
  __shared__ __align__(16) char smem[4 * SLICE_B];

  const int tid = threadIdx.x;
  const int w = tid >> 6;  // wave id == j-split s
  const int lane = tid & 63;
  const int quad = lane >> 4, lm = lane & 15;

  float* Ds = (float*)(smem + w * SLICE_B);                           // [32][66]
  unsigned short* Ps = (unsigned short*)(smem + w * SLICE_B + 8448);  // [32][40]
  float* dbv = (float*)(smem + w * SLICE_B + 8448 + 2560);            // [32]
  // pure-path Ds read base: idx = 1040*t + 65*lm + 4*quad + 16*mt + rg + 31
  const float* DsL = Ds + lm * 65 + quad * 4;

  // block -> (batch pinned to XCD, pair)
  const int xcd = blockIdx.x & 7;
  const int slot = blockIdx.x >> 3;        // 0..63
  const int b = xcd + ((slot & 1) << 3);
  const int pr = slot >> 1;                // pair 0..31
  const int s = w;

  const size_t qoff = (size_t)b * (2048 * 64);
  const unsigned short* qB = qb + qoff;
  const unsigned short* kB = kb + qoff;
  const unsigned short* vB = vT + qoff;  // [H][T]

  // Er[2047] B-frag for the diagonal-bias MFMA (col 0 only) — block constant
  short8 ebf[2];
#pragma unroll
  for (int kc = 0; kc < 2; kc++) {
    short8 z = (short8){0, 0, 0, 0, 0, 0, 0, 0};
    if (lm == 0)
      z = *(const short8*)&Erb[(size_t)2047 * 64 + kc * 32 + quad * 8];
    ebf[kc] = z;
  }

  for (int ph = 0; ph < 2; ph++) {
    const int it = ph ? (63 - pr) : pr;
    const int i0 = it * 32;

    // Q A-frags for the wave's 32 rows, held in registers
    short8 qf[2][2];
#pragma unroll
    for (int mt = 0; mt < 2; mt++)
#pragma unroll
      for (int kc = 0; kc < 2; kc++)
        qf[mt][kc] =
            *(const short8*)&qB[(size_t)(i0 + mt * 16 + lm) * 64 + kc * 32 + quad * 8];

    // diagonal bias: only the wave that owns the diagonal tile needs it
    if ((it & (NSPLIT - 1)) == w) {
#pragma unroll
      for (int mt = 0; mt < 2; mt++) {
        floatx4 dacc = (floatx4){0.f, 0.f, 0.f, 0.f};
        dacc = __builtin_amdgcn_mfma_f32_16x16x32_bf16(qf[mt][0], ebf[0], dacc, 0, 0, 0);
        dacc = __builtin_amdgcn_mfma_f32_16x16x32_bf16(qf[mt][1], ebf[1], dacc, 0, 0, 0);
        if (lm == 0) {
#pragma unroll
          for (int rg = 0; rg < 4; rg++)
            dbv[mt * 16 + quad * 4 + rg] = dacc[rg];
        }
      }
    }

    floatx4 O[2][4];
#pragma unroll
    for (int mt = 0; mt < 2; mt++)
#pragma unroll
      for (int nt = 0; nt < 4; nt++) O[mt][nt] = (floatx4){0.f, 0.f, 0.f, 0.f};
    float m_st[2][4], l_st[2][4];  // l_st is a per-lane partial sum
#pragma unroll
    for (int mt = 0; mt < 2; mt++)
#pragma unroll
      for (int rg = 0; rg < 4; rg++) { m_st[mt][rg] = -1e30f; l_st[mt][rg] = 0.f; }

    // loop-carried K/U/E frags (rotated prefetch, single buffer)
    short8 kf[2][2], uf[2][2], ef[4][2];
    auto LOADKUE = [&](int jn) {
      const int j0n = jn * 32;
      const int dn = i0 - j0n;
      const int e0n = (dn - 33 > 0) ? (dn - 33) : 0;
#pragma unroll
      for (int t = 0; t < 2; t++)
#pragma unroll
        for (int kc = 0; kc < 2; kc++)
          kf[t][kc] =
              *(const short8*)&kB[(size_t)(j0n + t * 16 + lm) * 64 + kc * 32 + quad * 8];
#pragma unroll
      for (int ct = 0; ct < 2; ct++)
#pragma unroll
        for (int kc = 0; kc < 2; kc++)
          uf[ct][kc] = *(const short8*)&qB[(size_t)(j0n + ct * 16 + lm + 1) * 64 +
                                           kc * 32 + quad * 8];
#pragma unroll
      for (int et = 0; et < 4; et++)
#pragma unroll
        for (int kc = 0; kc < 2; kc++)
          ef[et][kc] = *(const short8*)&Erb[(size_t)(e0n + et * 16 + lm) * 64 +
                                            kc * 32 + quad * 8];
    };
    if (s <= it) LOADKUE(s);

    for (int jt = s; jt <= it; jt += NSPLIT) {
      const int j0 = jt * 32;
      const int d = i0 - j0;
      const int e0 = (d - 33 > 0) ? (d - 33) : 0;

      // V frags for THIS tile: consumed at PV (end of body) — latency hidden
      short8 vf[4];
#pragma unroll
      for (int nt = 0; nt < 4; nt++)
        vf[nt] = *(const short8*)&vB[(size_t)(nt * 16 + lm) * 2048 + j0 + quad * 8];

      // D band: D[c][e] = q_{j0+1+c} . Er[e0+e]   (32 x 64)
#pragma unroll
      for (int ct = 0; ct < 2; ct++)
#pragma unroll
        for (int et = 0; et < 4; et++) {
          floatx4 dacc = (floatx4){0.f, 0.f, 0.f, 0.f};
          dacc = __builtin_amdgcn_mfma_f32_16x16x32_bf16(uf[ct][0], ef[et][0], dacc, 0, 0, 0);
          dacc = __builtin_amdgcn_mfma_f32_16x16x32_bf16(uf[ct][1], ef[et][1], dacc, 0, 0, 0);
#pragma unroll
          for (int rg = 0; rg < 4; rg++)
            Ds[(ct * 16 + quad * 4 + rg) * 66 + et * 16 + lm] = dacc[rg];
        }

      // qk
      floatx4 S[2][2];
#pragma unroll
      for (int mt = 0; mt < 2; mt++)
#pragma unroll
        for (int t = 0; t < 2; t++) {
          floatx4 a = (floatx4){0.f, 0.f, 0.f, 0.f};
          a = __builtin_amdgcn_mfma_f32_16x16x32_bf16(qf[mt][0], kf[t][0], a, 0, 0, 0);
          a = __builtin_amdgcn_mfma_f32_16x16x32_bf16(qf[mt][1], kf[t][1], a, 0, 0, 0);
          S[mt][t] = a;
        }

      // prefetch next tile's K/U/E (kf/uf/ef last used above) —
      // L2 latency hides under softmax + PV below
      if (jt + NSPLIT <= it) LOADKUE(jt + NSPLIT);

      // scores (pure tiles: static-offset Ds reads, no masking)
      float sv0[8], sv1[8], lmx[8];
      bool allok = true;
      if (d >= 64) {
#pragma unroll
        for (int mt = 0; mt < 2; mt++)
#pragma unroll
          for (int rg = 0; rg < 4; rg++) {
            const int c = mt * 4 + rg;
            float d0 = DsL[mt * 16 + rg + 31];
            float d1 = DsL[1040 + mt * 16 + rg + 31];
            sv0[c] = fmaf(0.125f, S[mt][0][rg], d0);
            sv1[c] = fmaf(0.125f, S[mt][1][rg], d1);
            lmx[c] = fmaxf(sv0[c], sv1[c]);
            allok = allok && (lmx[c] <= m_st[mt][rg] + 8.f);
          }
      } else {
#pragma unroll
        for (int mt = 0; mt < 2; mt++)
#pragma unroll
          for (int rg = 0; rg < 4; rg++) {
            const int c = mt * 4 + rg;
            const int rloc = mt * 16 + quad * 4 + rg;
            const int i = i0 + rloc;
            float v0, v1;
            {
              int j = j0 + lm;
              float raw = 0.125f * S[mt][0][rg];
              if (j > i) v0 = -1e30f;
              else if (j == i) v0 = raw + dbv[rloc];
              else if (j == i - 1) v0 = raw;
              else v0 = raw + Ds[lm * 66 + (i - j - 2 - e0)];
            }
            {
              int j = j0 + 16 + lm;
              float raw = 0.125f * S[mt][1][rg];
              if (j > i) v1 = -1e30f;
              else if (j == i) v1 = raw + dbv[rloc];
              else if (j == i - 1) v1 = raw;
              else v1 = raw + Ds[(16 + lm) * 66 + (i - j - 2 - e0)];
            }
            sv0[c] = v0; sv1[c] = v1;
            lmx[c] = fmaxf(v0, v1);
            allok = allok && (lmx[c] <= m_st[mt][rg] + 8.f);
          }
      }

      if (__all((int)allok)) {
        // FAST PATH: no cross-lane ops, no rescale
#pragma unroll
        for (int mt = 0; mt < 2; mt++)
#pragma unroll
          for (int rg = 0; rg < 4; rg++) {
            const int c = mt * 4 + rg;
            const int rloc = mt * 16 + quad * 4 + rg;
            float p0 = __expf(sv0[c] - m_st[mt][rg]);
            float p1 = __expf(sv1[c] - m_st[mt][rg]);
            l_st[mt][rg] += p0 + p1;
            Ps[rloc * 40 + lm] = f2bf(p0);
            Ps[rloc * 40 + 16 + lm] = f2bf(p1);
          }
      } else {
        // SLOW PATH: shuffle max-reduce + rescale
#pragma unroll
        for (int mt = 0; mt < 2; mt++)
#pragma unroll
          for (int rg = 0; rg < 4; rg++) {
            const int c = mt * 4 + rg;
            const int rloc = mt * 16 + quad * 4 + rg;
            float mx = lmx[c];
            mx = fmaxf(mx, __shfl_xor(mx, 1));
            mx = fmaxf(mx, __shfl_xor(mx, 2));
            mx = fmaxf(mx, __shfl_xor(mx, 4));
            mx = fmaxf(mx, __shfl_xor(mx, 8));
            float m_new = fmaxf(m_st[mt][rg], mx);
            float alpha = __expf(m_st[mt][rg] - m_new);
            float p0 = __expf(sv0[c] - m_new);
            float p1 = __expf(sv1[c] - m_new);
            l_st[mt][rg] = l_st[mt][rg] * alpha + (p0 + p1);
            m_st[mt][rg] = m_new;
#pragma unroll
            for (int nt = 0; nt < 4; nt++) O[mt][nt][rg] *= alpha;
            Ps[rloc * 40 + lm] = f2bf(p0);
            Ps[rloc * 40 + 16 + lm] = f2bf(p1);
          }
      }

      // PV (Ps RAW: in-order DS pipe; compiler waits on read data)
#pragma unroll
      for (int mt = 0; mt < 2; mt++) {
        short8 pa = *(const short8*)&Ps[(mt * 16 + lm) * 40 + quad * 8];
#pragma unroll
        for (int nt = 0; nt < 4; nt++)
          O[mt][nt] = __builtin_amdgcn_mfma_f32_16x16x32_bf16(pa, vf[nt], O[mt][nt], 0, 0, 0);
      }
    }

    // ---- phase epilogue: in-block merge of the 4 j-splits ----
    {
      float* Os = (float*)(smem + w * SLICE_B);
      float* mlm = (float*)(smem + w * SLICE_B + 8448);
      float* mll = (float*)(smem + w * SLICE_B + 8448 + 128);
#pragma unroll
      for (int mt = 0; mt < 2; mt++)
#pragma unroll
        for (int rg = 0; rg < 4; rg++) {
          float lr = l_st[mt][rg];
          lr += __shfl_xor(lr, 1);
          lr += __shfl_xor(lr, 2);
          lr += __shfl_xor(lr, 4);
          lr += __shfl_xor(lr, 8);
          const int rloc = mt * 16 + quad * 4 + rg;
          if (lm == 0) { mlm[rloc] = m_st[mt][rg]; mll[rloc] = lr; }
#pragma unroll
          for (int nt = 0; nt < 4; nt++)
            Os[rloc * 65 + nt * 16 + lm] = O[mt][nt][rg];
        }
    }
    __syncthreads();
    {
      const int row = tid >> 3, c0 = (tid & 7) * 8;
      float mstar = -1e30f;
#pragma unroll
      for (int s2 = 0; s2 < 4; s2++)
        mstar = fmaxf(mstar, *(const float*)(smem + s2 * SLICE_B + 8448 + row * 4));
      float den = 0.f;
      float acc[8];
#pragma unroll
      for (int c = 0; c < 8; c++) acc[c] = 0.f;
#pragma unroll
      for (int s2 = 0; s2 < 4; s2++) {
        const char* sl = smem + s2 * SLICE_B;
        float ms = *(const float*)(sl + 8448 + row * 4);
        float ls = *(const float*)(sl + 8448 + 128 + row * 4);
        float a = __expf(ms - mstar);
        den += a * ls;
        const float* osp = (const float*)sl + row * 65 + c0;
#pragma unroll
        for (int c = 0; c < 8; c++) acc[c] += a * osp[c];
      }
      float inv = 1.f / den;
      float4 r0 = {acc[0] * inv, acc[1] * inv, acc[2] * inv, acc[3] * inv};
      float4 r1 = {acc[4] * inv, acc[5] * inv, acc[6] * inv, acc[7] * inv};
      float* po = &out[qoff + (size_t)(i0 + row) * 64 + c0];
      *(float4*)po = r0;
      *((float4*)po + 1) = r1;
    }
    __syncthreads();  // slices reused by next phase
  }
}

extern "C" void kernel_launch(void* const* d_in, const int* in_sizes, int n_in,
                              void* d_out, int out_size, void* d_ws,
                              size_t ws_size, hipStream_t stream) {
  const float* x = (const float*)d_in[0];
  const float* Wq = (const float*)d_in[1];
  const float* Wk = (const float*)d_in[2];
  const float* Wv = (const float*)d_in[3];
  const float* Er = (const float*)d_in[4];
  float* out = (float*)d_out;

  unsigned short* qb = (unsigned short*)d_ws;  // 2M elems = 4 MB
  unsigned short* kb = qb + 2097152;
  unsigned short* vT = kb + 2097152;
  unsigned short* Wt = vT + 2097152;   // 98304 elems
  unsigned short* Erb = Wt + 98304;    // 131072 elems; total 13,041,664 B

  prep_kernel<<<576, 256, 0, stream>>>(Wq, Wk, Wv, Er, Wt, Erb);
  proj_kernel<<<512, 256, 0, stream>>>(x, Wt, qb, kb, vT);
  // 512 blocks = 16 batches x 32 pairs; 4 waves/block = 4 j-splits;
  // in-block merge -> direct out, no combine kernel.
  attn_kernel<<<512, 256, 0, stream>>>(qb, kb, vT, Erb, out);
}

// Round 7
// 230.277 us; speedup vs baseline: 1.1015x; 1.1015x over previous
//
#include <hip/hip_runtime.h>
#include <hip/hip_bf16.h>

#define TT 2048
#define HB 64
#define NB 16
#define NSPLIT 4

typedef __attribute__((ext_vector_type(8))) short short8;
typedef __attribute__((ext_vector_type(4))) float floatx4;

static __device__ __forceinline__ unsigned short f2bf(float f) {
  __hip_bfloat16 h = __float2bfloat16(f);
  return *reinterpret_cast<unsigned short*>(&h);
}
static __device__ __forceinline__ float bf2f(unsigned short u) {
  __hip_bfloat16 h = *reinterpret_cast<__hip_bfloat16*>(&u);
  return __bfloat162float(h);
}

// ---------------------------------------------------------------------------
// Prep: Wt[mat][n][k] = bf16(W[k][n])  (3x64x512), Erb = bf16(Er) (2048x64).
// ---------------------------------------------------------------------------
__global__ __launch_bounds__(256) void prep_kernel(
    const float* __restrict__ Wq, const float* __restrict__ Wk,
    const float* __restrict__ Wv, const float* __restrict__ Er,
    unsigned short* __restrict__ Wt, unsigned short* __restrict__ Erb) {
  const int bx = blockIdx.x, tid = threadIdx.x;
  if (bx < 512) {
    int idx = bx * 256 + tid;
    Erb[idx] = f2bf(Er[idx]);
  } else {
    int n = bx - 512;  // 0..63
    const float* Ws[3] = {Wq, Wk, Wv};
#pragma unroll
    for (int m = 0; m < 3; m++)
      for (int k = tid; k < 512; k += 256)
        Wt[(size_t)(m * 64 + n) * 512 + k] = f2bf(Ws[m][(size_t)k * 64 + n]);
  }
}

// ---------------------------------------------------------------------------
// Projections via MFMA, no LDS. Block 256 (4 waves), 64 rows/block,
// 16 rows/wave, 12 n-tiles (q:0-3, k:4-7, v:8-11). A-frags from global x
// (fp32->bf16 in regs) with DOUBLE-BUFFERED prefetch (afA/afB) so the next
// kt-step's x loads are in flight under the current 24 MFMAs.
// B-frags from Wt (L2). vT stored [B][H][T].
// ---------------------------------------------------------------------------
__global__ __launch_bounds__(256) void proj_kernel(
    const float* __restrict__ x, const unsigned short* __restrict__ Wt,
    unsigned short* __restrict__ qb, unsigned short* __restrict__ kb,
    unsigned short* __restrict__ vT) {
  const int tid = threadIdx.x;
  const int w = tid >> 6, l = tid & 63, quad = l >> 4, lm = l & 15;
  const int m0 = blockIdx.x * 64;
  const int row_a = m0 + w * 16 + lm;

  floatx4 acc[12];
#pragma unroll
  for (int i = 0; i < 12; i++) acc[i] = (floatx4){0.f, 0.f, 0.f, 0.f};

  auto LDA = [&](short8* af, int kt) {
#pragma unroll
    for (int kc = 0; kc < 2; kc++) {
      const float* px = &x[(size_t)row_a * 512 + kt + kc * 32 + quad * 8];
      float4 f0 = *(const float4*)px;
      float4 f1 = *(const float4*)(px + 4);
      short8 s;
      s[0] = f2bf(f0.x); s[1] = f2bf(f0.y); s[2] = f2bf(f0.z); s[3] = f2bf(f0.w);
      s[4] = f2bf(f1.x); s[5] = f2bf(f1.y); s[6] = f2bf(f1.z); s[7] = f2bf(f1.w);
      af[kc] = s;
    }
  };
  auto MFMAS = [&](const short8* af, int kt) {
#pragma unroll
    for (int nt = 0; nt < 12; nt++) {
      const unsigned short* pw =
          &Wt[(size_t)((nt >> 2) * 64 + (nt & 3) * 16 + lm) * 512 + kt + quad * 8];
      short8 b0 = *(const short8*)pw;
      short8 b1 = *(const short8*)(pw + 32);
      acc[nt] = __builtin_amdgcn_mfma_f32_16x16x32_bf16(af[0], b0, acc[nt], 0, 0, 0);
      acc[nt] = __builtin_amdgcn_mfma_f32_16x16x32_bf16(af[1], b1, acc[nt], 0, 0, 0);
    }
  };

  short8 afA[2], afB[2];
  LDA(afA, 0);
#pragma unroll
  for (int kt = 0; kt < 512; kt += 128) {
    LDA(afB, kt + 64);   // prefetch: hides under afA's MFMAs
    MFMAS(afA, kt);
    if (kt + 128 < 512) LDA(afA, kt + 128);  // prefetch under afB's MFMAs
    MFMAS(afB, kt + 64);
  }

  const int b = m0 >> 11;
#pragma unroll
  for (int nt = 0; nt < 12; nt++) {
    int col = (nt & 3) * 16 + lm;
#pragma unroll
    for (int rg = 0; rg < 4; rg++) {
      int row = m0 + w * 16 + quad * 4 + rg;
      unsigned short hv = f2bf(acc[nt][rg]);
      if (nt < 4) qb[(size_t)row * 64 + col] = hv;
      else if (nt < 8) kb[(size_t)row * 64 + col] = hv;
      else vT[(size_t)(b * 64 + col) * 2048 + (row & 2047)] = hv;
    }
  }
}

// ---------------------------------------------------------------------------
// Flash relative attention. Block = 4 waves = the 4 j-splits of one
// (batch, pair): phase 0 = i-tile pr, phase 1 = i-tile 63-pr. Uniform work,
// 512 blocks (2/CU), in-block split merge, direct out write.
// R5-proven schedule (in-body loads, short live ranges, lgkm fences).
// PURE-TILE PATH (d>=64, all but <=1 tile/wave-phase): no masking/branches;
// Ds gather collapses to per-lane base + static offsets (66-stride write
// minus diagonal shear = effective 65-stride read; verified R6).
// DEFER-MAX (THR=8) fast path. dbv computed only by the diagonal-owning
// wave (it&3==w). Batches {x,x+8} pinned to XCD x.
//   S[i][j] = 0.125*(q_i.k_j) + [ db_i (j==i) | 0 (j==i-1) |
//                                 q_{j+1}.Er[i-j-2] (j<=i-2) ]
// ---------------------------------------------------------------------------
#define SLICE_B 11264  // per-wave slice: Ds 8448 | Ps 2560 | dbv 128
                       // epilogue reuse: Os [32][65] f32 (8320) | m/l 256

__global__ __launch_bounds__(256, 2) void attn_kernel(
    const unsigned short* __restrict__ qb, const unsigned short* __restrict__ kb,
    const unsigned short* __restrict__ vT, const unsigned short* __restrict__ Erb,
    float* __restrict__ out) {
  __shared__ __align__(16) char smem[4 * SLICE_B];

  const int tid = threadIdx.x;
  const int w = tid >> 6;  // wave id == j-split s
  const int lane = tid & 63;
  const int quad = lane >> 4, lm = lane & 15;

  float* Ds = (float*)(smem + w * SLICE_B);                           // [32][66]
  unsigned short* Ps = (unsigned short*)(smem + w * SLICE_B + 8448);  // [32][40]
  float* dbv = (float*)(smem + w * SLICE_B + 8448 + 2560);            // [32]
  // pure-path read base: Ds[(t*16+lm)*66 + (r - (t*16+lm) + 31)]
  //                    = DsL[1040*t + 16*mt + rg + 31]
  const float* DsL = Ds + lm * 65 + quad * 4;

  // block -> (batch pinned to XCD, pair)
  const int xcd = blockIdx.x & 7;
  const int slot = blockIdx.x >> 3;        // 0..63
  const int b = xcd + ((slot & 1) << 3);
  const int pr = slot >> 1;                // pair 0..31
  const int s = w;

  const size_t qoff = (size_t)b * (2048 * 64);
  const unsigned short* qB = qb + qoff;
  const unsigned short* kB = kb + qoff;
  const unsigned short* vB = vT + qoff;  // [H][T]

  // Er[2047] B-frag for the diagonal-bias MFMA (col 0 only) — block constant
  short8 ebf[2];
#pragma unroll
  for (int kc = 0; kc < 2; kc++) {
    short8 z = (short8){0, 0, 0, 0, 0, 0, 0, 0};
    if (lm == 0)
      z = *(const short8*)&Erb[(size_t)2047 * 64 + kc * 32 + quad * 8];
    ebf[kc] = z;
  }

  for (int ph = 0; ph < 2; ph++) {
    const int it = ph ? (63 - pr) : pr;
    const int i0 = it * 32;

    // Q A-frags for the wave's 32 rows, held in registers
    short8 qf[2][2];
#pragma unroll
    for (int mt = 0; mt < 2; mt++)
#pragma unroll
      for (int kc = 0; kc < 2; kc++)
        qf[mt][kc] =
            *(const short8*)&qB[(size_t)(i0 + mt * 16 + lm) * 64 + kc * 32 + quad * 8];

    // diagonal bias: only the wave owning the diagonal tile reads dbv
    if ((it & (NSPLIT - 1)) == w) {
#pragma unroll
      for (int mt = 0; mt < 2; mt++) {
        floatx4 dacc = (floatx4){0.f, 0.f, 0.f, 0.f};
        dacc = __builtin_amdgcn_mfma_f32_16x16x32_bf16(qf[mt][0], ebf[0], dacc, 0, 0, 0);
        dacc = __builtin_amdgcn_mfma_f32_16x16x32_bf16(qf[mt][1], ebf[1], dacc, 0, 0, 0);
        if (lm == 0) {
#pragma unroll
          for (int rg = 0; rg < 4; rg++)
            dbv[mt * 16 + quad * 4 + rg] = dacc[rg];
        }
      }
    }
    __builtin_amdgcn_wave_barrier();

    floatx4 O[2][4];
#pragma unroll
    for (int mt = 0; mt < 2; mt++)
#pragma unroll
      for (int nt = 0; nt < 4; nt++) O[mt][nt] = (floatx4){0.f, 0.f, 0.f, 0.f};
    float m_st[2][4], l_st[2][4];  // l_st is a per-lane partial sum
#pragma unroll
    for (int mt = 0; mt < 2; mt++)
#pragma unroll
      for (int rg = 0; rg < 4; rg++) { m_st[mt][rg] = -1e30f; l_st[mt][rg] = 0.f; }

    for (int jt = s; jt <= it; jt += NSPLIT) {
      const int j0 = jt * 32;
      const int d = i0 - j0;
      const int e0 = (d - 33 > 0) ? (d - 33) : 0;  // band [e0, e0+63] in-range

      // direct global frag loads (bf16, L2 hits via XCD pinning)
      short8 kf[2][2], uf[2][2], ef[4][2], vf[4];
#pragma unroll
      for (int t = 0; t < 2; t++)
#pragma unroll
        for (int kc = 0; kc < 2; kc++)
          kf[t][kc] =
              *(const short8*)&kB[(size_t)(j0 + t * 16 + lm) * 64 + kc * 32 + quad * 8];
#pragma unroll
      for (int ct = 0; ct < 2; ct++)
#pragma unroll
        for (int kc = 0; kc < 2; kc++) {
          int ur = j0 + ct * 16 + lm + 1;
          if (ur > 2047) ur = 2047;  // value unused (masked/diag cols)
          uf[ct][kc] = *(const short8*)&qB[(size_t)ur * 64 + kc * 32 + quad * 8];
        }
#pragma unroll
      for (int et = 0; et < 4; et++)
#pragma unroll
        for (int kc = 0; kc < 2; kc++)
          ef[et][kc] = *(const short8*)&Erb[(size_t)(e0 + et * 16 + lm) * 64 +
                                            kc * 32 + quad * 8];
#pragma unroll
      for (int nt = 0; nt < 4; nt++)
        vf[nt] = *(const short8*)&vB[(size_t)(nt * 16 + lm) * 2048 + j0 + quad * 8];

      __builtin_amdgcn_wave_barrier();  // WAR: prev iter's Ds/Ps reads first

      // D band: D[c][e] = q_{j0+1+c} . Er[e0+e]   (32 x 64)
#pragma unroll
      for (int ct = 0; ct < 2; ct++)
#pragma unroll
        for (int et = 0; et < 4; et++) {
          floatx4 dacc = (floatx4){0.f, 0.f, 0.f, 0.f};
          dacc = __builtin_amdgcn_mfma_f32_16x16x32_bf16(uf[ct][0], ef[et][0], dacc, 0, 0, 0);
          dacc = __builtin_amdgcn_mfma_f32_16x16x32_bf16(uf[ct][1], ef[et][1], dacc, 0, 0, 0);
#pragma unroll
          for (int rg = 0; rg < 4; rg++)
            Ds[(ct * 16 + quad * 4 + rg) * 66 + et * 16 + lm] = dacc[rg];
        }

      // qk
      floatx4 S[2][2];
#pragma unroll
      for (int mt = 0; mt < 2; mt++)
#pragma unroll
        for (int t = 0; t < 2; t++) {
          floatx4 a = (floatx4){0.f, 0.f, 0.f, 0.f};
          a = __builtin_amdgcn_mfma_f32_16x16x32_bf16(qf[mt][0], kf[t][0], a, 0, 0, 0);
          a = __builtin_amdgcn_mfma_f32_16x16x32_bf16(qf[mt][1], kf[t][1], a, 0, 0, 0);
          S[mt][t] = a;
        }

      __builtin_amdgcn_wave_barrier();  // Ds RAW (cross-lane, same wave)
      asm volatile("s_waitcnt lgkmcnt(0)" ::: "memory");
      __builtin_amdgcn_sched_barrier(0);

      // scores
      float sv0[8], sv1[8], lmx[8];
      bool allok = true;
      if (d >= 64) {
        // PURE TILES: no masking, static-offset Ds reads
#pragma unroll
        for (int mt = 0; mt < 2; mt++)
#pragma unroll
          for (int rg = 0; rg < 4; rg++) {
            const int c = mt * 4 + rg;
            float d0 = DsL[mt * 16 + rg + 31];
            float d1 = DsL[1040 + mt * 16 + rg + 31];
            sv0[c] = fmaf(0.125f, S[mt][0][rg], d0);
            sv1[c] = fmaf(0.125f, S[mt][1][rg], d1);
            lmx[c] = fmaxf(sv0[c], sv1[c]);
            allok = allok && (lmx[c] <= m_st[mt][rg] + 8.f);
          }
      } else {
#pragma unroll
        for (int mt = 0; mt < 2; mt++)
#pragma unroll
          for (int rg = 0; rg < 4; rg++) {
            const int c = mt * 4 + rg;
            const int rloc = mt * 16 + quad * 4 + rg;
            const int i = i0 + rloc;
            float v0, v1;
            {
              int j = j0 + lm;
              float raw = 0.125f * S[mt][0][rg];
              if (j > i) v0 = -1e30f;
              else if (j == i) v0 = raw + dbv[rloc];
              else if (j == i - 1) v0 = raw;
              else v0 = raw + Ds[lm * 66 + (i - j - 2 - e0)];
            }
            {
              int j = j0 + 16 + lm;
              float raw = 0.125f * S[mt][1][rg];
              if (j > i) v1 = -1e30f;
              else if (j == i) v1 = raw + dbv[rloc];
              else if (j == i - 1) v1 = raw;
              else v1 = raw + Ds[(16 + lm) * 66 + (i - j - 2 - e0)];
            }
            sv0[c] = v0; sv1[c] = v1;
            lmx[c] = fmaxf(v0, v1);
            allok = allok && (lmx[c] <= m_st[mt][rg] + 8.f);
          }
      }

      if (__all((int)allok)) {
        // FAST PATH: no cross-lane ops, no rescale
#pragma unroll
        for (int mt = 0; mt < 2; mt++)
#pragma unroll
          for (int rg = 0; rg < 4; rg++) {
            const int c = mt * 4 + rg;
            const int rloc = mt * 16 + quad * 4 + rg;
            float p0 = __expf(sv0[c] - m_st[mt][rg]);
            float p1 = __expf(sv1[c] - m_st[mt][rg]);
            l_st[mt][rg] += p0 + p1;
            Ps[rloc * 40 + lm] = f2bf(p0);
            Ps[rloc * 40 + 16 + lm] = f2bf(p1);
          }
      } else {
        // SLOW PATH: shuffle max-reduce + rescale
#pragma unroll
        for (int mt = 0; mt < 2; mt++)
#pragma unroll
          for (int rg = 0; rg < 4; rg++) {
            const int c = mt * 4 + rg;
            const int rloc = mt * 16 + quad * 4 + rg;
            float mx = lmx[c];
            mx = fmaxf(mx, __shfl_xor(mx, 1));
            mx = fmaxf(mx, __shfl_xor(mx, 2));
            mx = fmaxf(mx, __shfl_xor(mx, 4));
            mx = fmaxf(mx, __shfl_xor(mx, 8));
            float m_new = fmaxf(m_st[mt][rg], mx);
            float alpha = __expf(m_st[mt][rg] - m_new);
            float p0 = __expf(sv0[c] - m_new);
            float p1 = __expf(sv1[c] - m_new);
            l_st[mt][rg] = l_st[mt][rg] * alpha + (p0 + p1);
            m_st[mt][rg] = m_new;
#pragma unroll
            for (int nt = 0; nt < 4; nt++) O[mt][nt][rg] *= alpha;
            Ps[rloc * 40 + lm] = f2bf(p0);
            Ps[rloc * 40 + 16 + lm] = f2bf(p1);
          }
      }

      __builtin_amdgcn_wave_barrier();  // Ps RAW (cross-lane, same wave)
      asm volatile("s_waitcnt lgkmcnt(0)" ::: "memory");
      __builtin_amdgcn_sched_barrier(0);

      // PV
#pragma unroll
      for (int mt = 0; mt < 2; mt++) {
        short8 pa = *(const short8*)&Ps[(mt * 16 + lm) * 40 + quad * 8];
#pragma unroll
        for (int nt = 0; nt < 4; nt++)
          O[mt][nt] = __builtin_amdgcn_mfma_f32_16x16x32_bf16(pa, vf[nt], O[mt][nt], 0, 0, 0);
      }
    }

    // ---- phase epilogue: in-block merge of the 4 j-splits ----
    {
      float* Os = (float*)(smem + w * SLICE_B);
      float* mlm = (float*)(smem + w * SLICE_B + 8448);
      float* mll = (float*)(smem + w * SLICE_B + 8448 + 128);
#pragma unroll
      for (int mt = 0; mt < 2; mt++)
#pragma unroll
        for (int rg = 0; rg < 4; rg++) {
          float lr = l_st[mt][rg];
          lr += __shfl_xor(lr, 1);
          lr += __shfl_xor(lr, 2);
          lr += __shfl_xor(lr, 4);
          lr += __shfl_xor(lr, 8);
          const int rloc = mt * 16 + quad * 4 + rg;
          if (lm == 0) { mlm[rloc] = m_st[mt][rg]; mll[rloc] = lr; }
#pragma unroll
          for (int nt = 0; nt < 4; nt++)
            Os[rloc * 65 + nt * 16 + lm] = O[mt][nt][rg];
        }
    }
    __syncthreads();
    {
      const int row = tid >> 3, c0 = (tid & 7) * 8;
      float mstar = -1e30f;
#pragma unroll
      for (int s2 = 0; s2 < 4; s2++)
        mstar = fmaxf(mstar, *(const float*)(smem + s2 * SLICE_B + 8448 + row * 4));
      float den = 0.f;
      float acc[8];
#pragma unroll
      for (int c = 0; c < 8; c++) acc[c] = 0.f;
#pragma unroll
      for (int s2 = 0; s2 < 4; s2++) {
        const char* sl = smem + s2 * SLICE_B;
        float ms = *(const float*)(sl + 8448 + row * 4);
        float ls = *(const float*)(sl + 8448 + 128 + row * 4);
        float a = __expf(ms - mstar);
        den += a * ls;
        const float* osp = (const float*)sl + row * 65 + c0;
#pragma unroll
        for (int c = 0; c < 8; c++) acc[c] += a * osp[c];
      }
      float inv = 1.f / den;
      float4 r0 = {acc[0] * inv, acc[1] * inv, acc[2] * inv, acc[3] * inv};
      float4 r1 = {acc[4] * inv, acc[5] * inv, acc[6] * inv, acc[7] * inv};
      float* po = &out[qoff + (size_t)(i0 + row) * 64 + c0];
      *(float4*)po = r0;
      *((float4*)po + 1) = r1;
    }
    __syncthreads();  // slices reused by next phase
  }
}

extern "C" void kernel_launch(void* const* d_in, const int* in_sizes, int n_in,
                              void* d_out, int out_size, void* d_ws,
                              size_t ws_size, hipStream_t stream) {
  const float* x = (const float*)d_in[0];
  const float* Wq = (const float*)d_in[1];
  const float* Wk = (const float*)d_in[2];
  const float* Wv = (const float*)d_in[3];
  const float* Er = (const float*)d_in[4];
  float* out = (float*)d_out;

  unsigned short* qb = (unsigned short*)d_ws;  // 2M elems = 4 MB
  unsigned short* kb = qb + 2097152;
  unsigned short* vT = kb + 2097152;
  unsigned short* Wt = vT + 2097152;   // 98304 elems
  unsigned short* Erb = Wt + 98304;    // 131072 elems; total 13,041,664 B

  prep_kernel<<<576, 256, 0, stream>>>(Wq, Wk, Wv, Er, Wt, Erb);
  proj_kernel<<<512, 256, 0, stream>>>(x, Wt, qb, kb, vT);
  // 512 blocks = 16 batches x 32 pairs; 4 waves/block = 4 j-splits;
  // in-block merge -> direct out, no combine kernel.
  attn_kernel<<<512, 256, 0, stream>>>(qb, kb, vT, Erb, out);
}